// Round 3
// baseline (59.440 us; speedup 1.0000x reference)
//
#include <hip/hip_runtime.h>
#include <math.h>

// Problem constants (fixed by the reference)
#define B_   16
#define F_   32
#define NP_  128   // Np = FNP / F = 4096/32
#define D_   512
#define P_   16
#define KC   64            // K-chunk in floats (256 B per row per chunk)
#define NCH  (D_ / KC)     // 8 chunks

__global__ __launch_bounds__(512, 4)
void pd_kernel(const float* __restrict__ ts,
               const float* __restrict__ W,
               const float* __restrict__ bias,
               float* __restrict__ out, int T)
{
    // staging: 2 buffers x 128 rows x 64 floats = 64 KB; reused as raw_lds later
    __shared__ float smem[2 * NP_ * KC];

    const int tid  = threadIdx.x;
    const int lane = tid & 63;
    const int wave = tid >> 6;
    // wave -> (row half, e-group): rows (wave&1)*64+lane, e's 8*(wave>>1)..+7
    const int n    = ((wave & 1) << 6) + lane;            // this thread's row
    const int e0   = __builtin_amdgcn_readfirstlane((wave >> 1) << 3);

    // XCD-aware block-id encoding: d = (b&7) + 8*(f + 32*(b>>3))
    // => all 32 f's of one b land on the same XCD so strided output stores
    //    merge in that XCD's L2 (WRITE_SIZE measured at ideal 4.1 MB).
    const int d = blockIdx.x;
    const int b = (d & 7) | ((d >> 8) << 3);
    const int f = (d >> 3) & 31;
    const float* __restrict__ tsb = ts + ((size_t)b * F_ + f) * NP_ * D_;

    float acc[8];
#pragma unroll
    for (int eo = 0; eo < 8; ++eo) acc[eo] = 0.f;

    // ---- stage chunk 0 into buffer 0 (pre-swizzled global source, linear LDS dest)
#pragma unroll
    for (int it = 0; it < 4; ++it) {
        int slot = it * 512 + tid;           // 0..2047 16B-slots (128 rows x 16 quads)
        int rr = slot >> 4;
        int ql = slot & 15;
        int qg = ql ^ (rr & 7);              // XOR quad swizzle (bijective per row)
        const float* src = tsb + rr * D_ + (qg << 2);
        __builtin_amdgcn_global_load_lds(
            (const __attribute__((address_space(1))) unsigned int*)src,
            (__attribute__((address_space(3))) unsigned int*)&smem[slot << 2],
            16, 0, 0);
    }
    __syncthreads();

    const int sw = n & 7;

    for (int c = 0; c < NCH; ++c) {
        // ---- stage chunk c+1 into the other buffer (overlaps with compute below)
        if (c + 1 < NCH) {
            const int k0 = (c + 1) * KC;
            float* dstb = smem + ((c + 1) & 1) * (NP_ * KC);
#pragma unroll
            for (int it = 0; it < 4; ++it) {
                int slot = it * 512 + tid;
                int rr = slot >> 4;
                int ql = slot & 15;
                int qg = ql ^ (rr & 7);
                const float* src = tsb + rr * D_ + k0 + (qg << 2);
                __builtin_amdgcn_global_load_lds(
                    (const __attribute__((address_space(1))) unsigned int*)src,
                    (__attribute__((address_space(3))) unsigned int*)&dstb[slot << 2],
                    16, 0, 0);
            }
        }

        // ---- compute on current buffer: this thread's single row, 8 e's
        const float* row = smem + (c & 1) * (NP_ * KC) + n * KC;
        const int kb = c * KC;
#pragma unroll
        for (int h = 0; h < 2; ++h) {
            // register-prefetch 8 quads (32 floats) of the row -> pure-FMA phase after
            float4 r[8];
#pragma unroll
            for (int q8 = 0; q8 < 8; ++q8) {
                const int q = (h << 3) + q8;
                r[q8] = *(const float4*)(row + (((q ^ sw) & 15) << 2));
            }
#pragma unroll
            for (int eo = 0; eo < 8; ++eo) {
                // 32 CONSECUTIVE wave-uniform floats -> s_load_dwordx16 x2
                const float* we = W + (size_t)(e0 + eo) * D_ + kb + (h << 5);
#pragma unroll
                for (int q8 = 0; q8 < 8; ++q8) {
                    acc[eo] += r[q8].x * we[q8 * 4 + 0]
                             + r[q8].y * we[q8 * 4 + 1]
                             + r[q8].z * we[q8 * 4 + 2]
                             + r[q8].w * we[q8 * 4 + 3];
                }
            }
        }
        __syncthreads();   // drains stage(c+1) (vmcnt) + all ds_reads of buf (lgkm)
    }

    // ---- epilogue: raw -> LDS (padded stride 33, conflict-free), then gather
#pragma unroll
    for (int eo = 0; eo < 8; ++eo) {
        const int e = e0 + eo;
        float v = acc[eo] + bias[e];
        if (e >= P_) v = fmaxf(expf(v), 1e-6f);   // sigma half (wave-uniform branch)
        smem[n * 33 + e] = v;
    }
    __syncthreads();

    // out[b, t, f] = sum_{n: p=t-8n in [0,16)} raw[n][p (+16)] / count(t)
    const int TF = T * F_;
    const size_t halfoff = (size_t)B_ * TF;
    for (int item = tid; item < 2 * T; item += 512) {
        const int half = (item >= T) ? 1 : 0;
        const int t    = item - half * T;
        const int nmax = min(NP_ - 1, t >> 3);
        const int nmin = (t > 8) ? ((t - 8) >> 3) : 0;
        float sum = 0.f;
        const int cnt = nmax - nmin + 1;
        for (int nn = nmin; nn <= nmax; ++nn)
            sum += smem[nn * 33 + (half << 4) + (t - (nn << 3))];
        const float r = (cnt > 0) ? sum / (float)cnt : 0.f;
        out[(size_t)half * halfoff + (size_t)b * TF + (size_t)t * F_ + f] = r;
    }
}

extern "C" void kernel_launch(void* const* d_in, const int* in_sizes, int n_in,
                              void* d_out, int out_size, void* d_ws, size_t ws_size,
                              hipStream_t stream)
{
    const float* ts   = (const float*)d_in[0];
    const float* W    = (const float*)d_in[1];
    const float* bias = (const float*)d_in[2];
    float* out = (float*)d_out;

    // T derived on host from out_size = 2 * B * T * F
    const int T = out_size / (2 * B_ * F_);

    dim3 grid(B_ * F_);   // 512 blocks, one per (b, f), XCD-encoded id
    dim3 block(512);
    pd_kernel<<<grid, block, 0, stream>>>(ts, W, bias, out, T);
}